// Round 8
// baseline (1258.192 us; speedup 1.0000x reference)
//
#include <hip/hip_runtime.h>
#include <math.h>

#define CDIV(a,b) (((a)+(b)-1)/(b))

typedef unsigned short bfu;                                   // bf16 bits
typedef short   s16x8 __attribute__((ext_vector_type(8)));    // MFMA A/B frag (8 bf16)
typedef float   f32x4 __attribute__((ext_vector_type(4)));    // MFMA C/D frag

// async global->LDS, 16B per lane. LDS dst must be wave-uniform; HW writes base+lane*16.
#define GLOAD16(gp, lp) __builtin_amdgcn_global_load_lds( \
    (const __attribute__((address_space(1))) void*)(gp),  \
    (__attribute__((address_space(3))) void*)(lp), 16, 0, 0)

// ---------------------------------------------------------------- helpers
static __device__ __forceinline__ float gelu_exact(float x) {
    return 0.5f * x * (1.0f + erff(x * 0.7071067811865475f));
}
static __device__ __forceinline__ bfu f2bf(float x) {         // RNE f32->bf16
    unsigned int u = __float_as_uint(x);
    unsigned int r = u + 0x7fffu + ((u >> 16) & 1u);
    return (bfu)(r >> 16);
}
static __device__ __forceinline__ float bf2f(bfu b) {
    return __uint_as_float(((unsigned int)b) << 16);
}
static __device__ __forceinline__ float wave_sum(float v) {
    #pragma unroll
    for (int off = 32; off; off >>= 1) v += __shfl_xor(v, off, 64);
    return v;
}

// ---------------------------------------------------------------- fp32 -> bf16 convert (grid-stride)
__global__ __launch_bounds__(256)
void cvt_kernel(const float* __restrict__ in, bfu* __restrict__ out, int n4)
{
    int i = blockIdx.x * 256 + threadIdx.x;
    const int stride = gridDim.x * 256;
    for (; i < n4; i += stride) {
        float4 f = ((const float4*)in)[i];
        ushort4 o;
        o.x = f2bf(f.x); o.y = f2bf(f.y); o.z = f2bf(f.z); o.w = f2bf(f.w);
        ((ushort4*)out)[i] = o;
    }
}

// ---------------------------------------------------------------- fused weight convert (6 regions)
__global__ __launch_bounds__(256)
void cvt6_kernel(const float* __restrict__ s0, const float* __restrict__ s1,
                 const float* __restrict__ s2, const float* __restrict__ s3,
                 const float* __restrict__ s4, const float* __restrict__ s5,
                 bfu* __restrict__ dst)
{
    const int c0 = 524288;           // p1_w  1024*2048/4
    const int c1 = c0 + 65536;       // p2_w  256*1024/4
    const int c2 = c1 + 98304;       // in_proj 2*768*256/4
    const int c3 = c2 + 32768;       // out_proj 2*256*256/4
    const int c4 = c3 + 131072;      // lin1 2*1024*256/4
    const int c5 = c4 + 131072;      // lin2 2*256*1024/4
    int i = blockIdx.x * 256 + threadIdx.x;
    const int stride = gridDim.x * 256;
    for (; i < c5; i += stride) {
        const float* s; int base;
        if      (i < c0) { s = s0; base = 0;  }
        else if (i < c1) { s = s1; base = c0; }
        else if (i < c2) { s = s2; base = c1; }
        else if (i < c3) { s = s3; base = c2; }
        else if (i < c4) { s = s4; base = c3; }
        else             { s = s5; base = c4; }
        float4 f = ((const float4*)s)[i - base];
        ushort4 o;
        o.x = f2bf(f.x); o.y = f2bf(f.y); o.z = f2bf(f.z); o.w = f2bf(f.w);
        ((ushort4*)dst)[i] = o;
    }
}

// ---------------------------------------------------------------- sincos PE table [T,256]
__global__ __launch_bounds__(256)
void pe_kernel(float* __restrict__ pe)
{
    const int t = blockIdx.x;
    const int c = threadIdx.x;
    const float div = expf((float)(c & ~1) * (-9.210340371976184f / 256.0f));
    const float ang = (float)t * div;
    pe[t * 256 + c] = (c & 1) ? cosf(ang) : sinf(ang);
}

// ---------------------------------------------------------------- MFMA GEMM 256x256 deep pipeline
// C[M,N] = scale * epi(A[M,K] @ W[N,K]^T + bias). 256x256 tile, BK=32,
// 512 thr (8 waves 2Mx4N, each 128x64). 2-buf LDS, stage(t+2) at end of t,
// counted vmcnt(4). 3-term granule XOR swizzle (conflict-free frag reads):
//   LDS[r][s] holds global k-granule s ^ (r&3) ^ ((r>>2)&3); source and read
//   apply the same involution (rule #21 both-sides).
template<bool GELU_EP, bool OUT_BF16>
__global__ __launch_bounds__(512, 2)
void mfma_gemm256(const bfu* __restrict__ A, const bfu* __restrict__ W,
                  const float* __restrict__ bias, void* __restrict__ Cv,
                  int M, int N, int K, float scale, int ntx)
{
    __shared__ bfu lds[2][2][8192];   // [dbuf][0=A,1=W][256 rows x 32 elems]

    const int tid  = threadIdx.x;
    const int lane = tid & 63;
    const int wv   = tid >> 6;        // 0..7
    const int nwg  = gridDim.x;
    const int lid  = (nwg & 7) ? (int)blockIdx.x
                               : ((int)blockIdx.x & 7) * (nwg >> 3) + ((int)blockIdx.x >> 3);
    const int row0 = (lid / ntx) * 256;
    const int col0 = (lid % ntx) * 256;

    const int srow = wv * 16 + (lane >> 2);
    // staging source granule = (lane&3) ^ (srow&3) ^ ((srow>>2)&3)
    const int sk   = ((lane & 3) ^ ((lane >> 2) & 3) ^ (lane >> 4)) * 8;
    const bfu* aS0 = A + (size_t)(row0 + srow)       * K + sk;
    const bfu* aS1 = A + (size_t)(row0 + srow + 128) * K + sk;
    const bfu* wS0 = W + (size_t)(col0 + srow)       * K + sk;
    const bfu* wS1 = W + (size_t)(col0 + srow + 128) * K + sk;
    const int dOff = wv * 512;

    const int wr = wv >> 2, wc = wv & 3;
    const int fr = lane & 15;
    // read slot = g ^ (row&3) ^ ((row>>2)&3); row ≡ fr (mod 16)
    const int slot = (((lane >> 4) ^ (fr & 3) ^ ((fr >> 2) & 3))) * 8;

    f32x4 acc[8][4];
    #pragma unroll
    for (int i = 0; i < 8; ++i)
        #pragma unroll
        for (int j = 0; j < 4; ++j) acc[i][j] = (f32x4)0.f;

    const int nt = K >> 5;

#define STAGE256(b_, t_) do { \
    const size_t ko_ = (size_t)(t_) * 32; \
    GLOAD16(aS0 + ko_, &lds[b_][0][dOff]); \
    GLOAD16(aS1 + ko_, &lds[b_][0][4096 + dOff]); \
    GLOAD16(wS0 + ko_, &lds[b_][1][dOff]); \
    GLOAD16(wS1 + ko_, &lds[b_][1][4096 + dOff]); \
} while (0)

    STAGE256(0, 0);
    STAGE256(1, 1);

    int cur = 0;
    for (int t = 0; t < nt; ++t) {
        if (t + 1 < nt) asm volatile("s_waitcnt vmcnt(4)" ::: "memory");
        else            asm volatile("s_waitcnt vmcnt(0)" ::: "memory");
        asm volatile("s_barrier" ::: "memory");

        const bfu* Ab = lds[cur][0];
        const bfu* Wb = lds[cur][1];

        s16x8 bfr[4], afr[8];
        #pragma unroll
        for (int j = 0; j < 4; ++j)
            bfr[j] = *(const s16x8*)&Wb[(wc * 64 + j * 16 + fr) * 32 + slot];
        #pragma unroll
        for (int i = 0; i < 4; ++i)
            afr[i] = *(const s16x8*)&Ab[(wr * 128 + i * 16 + fr) * 32 + slot];

        __builtin_amdgcn_s_setprio(1);
        #pragma unroll
        for (int i = 0; i < 4; ++i)
            #pragma unroll
            for (int j = 0; j < 4; ++j)
                acc[i][j] = __builtin_amdgcn_mfma_f32_16x16x32_bf16(afr[i], bfr[j], acc[i][j], 0, 0, 0);
        __builtin_amdgcn_s_setprio(0);

        #pragma unroll
        for (int i = 4; i < 8; ++i)
            afr[i] = *(const s16x8*)&Ab[(wr * 128 + i * 16 + fr) * 32 + slot];

        __builtin_amdgcn_s_setprio(1);
        #pragma unroll
        for (int i = 4; i < 8; ++i)
            #pragma unroll
            for (int j = 0; j < 4; ++j)
                acc[i][j] = __builtin_amdgcn_mfma_f32_16x16x32_bf16(afr[i], bfr[j], acc[i][j], 0, 0, 0);
        __builtin_amdgcn_s_setprio(0);

        asm volatile("s_barrier" ::: "memory");
        if (t + 2 < nt) STAGE256(cur, t + 2);
        cur ^= 1;
    }
#undef STAGE256

    #pragma unroll
    for (int i = 0; i < 8; ++i) {
        const int r = row0 + wr * 128 + 16 * i + (lane >> 4) * 4;
        #pragma unroll
        for (int j = 0; j < 4; ++j) {
            const int c = col0 + wc * 64 + 16 * j + fr;
            if (c < N) {
                const float bsum = bias ? bias[c] : 0.f;
                #pragma unroll
                for (int rr = 0; rr < 4; ++rr) {
                    float v = acc[i][j][rr] + bsum;
                    if (GELU_EP) v = gelu_exact(v);
                    v *= scale;
                    if (OUT_BF16) ((bfu*)Cv)[(size_t)(r + rr) * N + c] = f2bf(v);
                    else          ((float*)Cv)[(size_t)(r + rr) * N + c] = v;
                }
            }
        }
    }
}

// ---------------------------------------------------------------- MFMA GEMM 128x256 + fused LayerNorm
// Y = LN( A[M,K] @ W[256,K]^T + bias (+R) ) [*lnw+lnb] (+PE)  -> Yf fp32, Yb bf16
// L2N: additionally row-l2-normalize the LN output and write ONLY Yb
// (for the final layer: fuses the head-side l2norm, h fp32 never written).
// Same pipeline/swizzle as mfma_gemm256; 3 gloads/stage -> vmcnt(3). 48KB LDS.
template<bool RES, bool ADD_PE, bool L2N>
__global__ __launch_bounds__(512, 2)
void mfma_gemm_ln(const bfu* __restrict__ A, const bfu* __restrict__ W,
                  const float* __restrict__ bias, const float* __restrict__ R,
                  const float* __restrict__ lnw, const float* __restrict__ lnb,
                  const float* __restrict__ pe, float* __restrict__ Yf,
                  bfu* __restrict__ Yb, int M, int K, int T)
{
    __shared__ bfu ldsA[2][4096];     // [dbuf][128 rows x 32]
    __shared__ bfu ldsW[2][8192];     // [dbuf][256 rows x 32]

    const int tid  = threadIdx.x;
    const int lane = tid & 63;
    const int wv   = tid >> 6;
    const int nwg  = gridDim.x;
    const int lid  = (nwg & 7) ? (int)blockIdx.x
                               : ((int)blockIdx.x & 7) * (nwg >> 3) + ((int)blockIdx.x >> 3);
    const int row0 = lid * 128;

    const int srow = wv * 16 + (lane >> 2);
    const int sk   = ((lane & 3) ^ ((lane >> 2) & 3) ^ (lane >> 4)) * 8;
    const bfu* aS  = A + (size_t)(row0 + srow) * K + sk;
    const bfu* wS0 = W + (size_t)(srow)        * K + sk;
    const bfu* wS1 = W + (size_t)(srow + 128)  * K + sk;
    const int dOff = wv * 512;

    const int wr = wv >> 2, wc = wv & 3;       // 2M x 4N, each wave 64x64
    const int fr = lane & 15;
    const int g4 = lane >> 4;
    const int slot = ((g4 ^ (fr & 3) ^ ((fr >> 2) & 3))) * 8;

    f32x4 acc[4][4];
    #pragma unroll
    for (int i = 0; i < 4; ++i)
        #pragma unroll
        for (int j = 0; j < 4; ++j) acc[i][j] = (f32x4)0.f;

    const int nt = K >> 5;

#define STAGELN(b_, t_) do { \
    const size_t ko_ = (size_t)(t_) * 32; \
    GLOAD16(aS  + ko_, &ldsA[b_][dOff]); \
    GLOAD16(wS0 + ko_, &ldsW[b_][dOff]); \
    GLOAD16(wS1 + ko_, &ldsW[b_][4096 + dOff]); \
} while (0)

    STAGELN(0, 0);
    STAGELN(1, 1);

    int cur = 0;
    for (int t = 0; t < nt; ++t) {
        if (t + 1 < nt) asm volatile("s_waitcnt vmcnt(3)" ::: "memory");
        else            asm volatile("s_waitcnt vmcnt(0)" ::: "memory");
        asm volatile("s_barrier" ::: "memory");

        const bfu* Ab = ldsA[cur];
        const bfu* Wb = ldsW[cur];

        s16x8 bfr[4], afr[4];
        #pragma unroll
        for (int j = 0; j < 4; ++j)
            bfr[j] = *(const s16x8*)&Wb[(wc * 64 + j * 16 + fr) * 32 + slot];
        #pragma unroll
        for (int i = 0; i < 4; ++i)
            afr[i] = *(const s16x8*)&Ab[(wr * 64 + i * 16 + fr) * 32 + slot];

        __builtin_amdgcn_s_setprio(1);
        #pragma unroll
        for (int i = 0; i < 4; ++i)
            #pragma unroll
            for (int j = 0; j < 4; ++j)
                acc[i][j] = __builtin_amdgcn_mfma_f32_16x16x32_bf16(afr[i], bfr[j], acc[i][j], 0, 0, 0);
        __builtin_amdgcn_s_setprio(0);

        asm volatile("s_barrier" ::: "memory");
        if (t + 2 < nt) STAGELN(cur, t + 2);
        cur ^= 1;
    }
#undef STAGELN

    // ---- fused LN epilogue (rows complete: 256 cols in-block) ----
    float* red   = (float*)ldsA;       // sum[128][4] @0, sq[128][4] @512
    float* stats = red + 1024;         // mean[128] @0, rstd[128] @128

    float bj[4];
    #pragma unroll
    for (int j = 0; j < 4; ++j)
        bj[j] = bias ? bias[wc * 64 + j * 16 + fr] : 0.f;

    #pragma unroll
    for (int i = 0; i < 4; ++i) {
        #pragma unroll
        for (int rr = 0; rr < 4; ++rr) {
            const int rl = wr * 64 + i * 16 + g4 * 4 + rr;
            const size_t r = (size_t)(row0 + rl);
            float s = 0.f, q = 0.f;
            #pragma unroll
            for (int j = 0; j < 4; ++j) {
                float v = acc[i][j][rr] + bj[j];
                if (RES) v += R[r * 256 + (wc * 64 + j * 16 + fr)];
                acc[i][j][rr] = v;
                s += v; q += v * v;
            }
            #pragma unroll
            for (int off = 1; off < 16; off <<= 1) {
                s += __shfl_xor(s, off, 64);
                q += __shfl_xor(q, off, 64);
            }
            if (fr == 0) { red[rl * 4 + wc] = s; red[512 + rl * 4 + wc] = q; }
        }
    }
    __syncthreads();
    if (tid < 128) {
        const float s = red[tid*4+0] + red[tid*4+1] + red[tid*4+2] + red[tid*4+3];
        const float q = red[512+tid*4+0] + red[512+tid*4+1] + red[512+tid*4+2] + red[512+tid*4+3];
        const float mean = s * (1.f / 256.f);
        const float var  = q * (1.f / 256.f) - mean * mean;
        stats[tid]       = mean;
        stats[128 + tid] = rsqrtf(var + 1e-6f);
    }
    __syncthreads();

    float lw[4], lb[4];
    #pragma unroll
    for (int j = 0; j < 4; ++j) {
        const int c = wc * 64 + j * 16 + fr;
        lw[j] = lnw[c]; lb[j] = lnb[c];
    }
    #pragma unroll
    for (int i = 0; i < 4; ++i) {
        #pragma unroll
        for (int rr = 0; rr < 4; ++rr) {
            const int rl = wr * 64 + i * 16 + g4 * 4 + rr;
            const size_t r = (size_t)(row0 + rl);
            const float mean = stats[rl], rstd = stats[128 + rl];
            const int tmod = (int)(r % (size_t)T);
            float ysq = 0.f;
            #pragma unroll
            for (int j = 0; j < 4; ++j) {
                const int c = wc * 64 + j * 16 + fr;
                float y = (acc[i][j][rr] - mean) * rstd * lw[j] + lb[j];
                if (ADD_PE) y += pe[tmod * 256 + c];
                if (!L2N) {
                    Yf[r * 256 + c] = y;
                    Yb[r * 256 + c] = f2bf(y);
                } else {
                    acc[i][j][rr] = y;
                    ysq += y * y;
                }
            }
            if (L2N) {
                #pragma unroll
                for (int off = 1; off < 16; off <<= 1) ysq += __shfl_xor(ysq, off, 64);
                if (fr == 0) red[rl * 4 + wc] = ysq;   // reuse (mean/rstd reads done after barrier)
            }
        }
    }
    if (L2N) {
        __syncthreads();
        if (tid < 128) {
            const float n = sqrtf(red[tid*4+0] + red[tid*4+1] + red[tid*4+2] + red[tid*4+3]);
            stats[tid] = 1.f / fmaxf(n, 1e-12f);
        }
        __syncthreads();
        #pragma unroll
        for (int i = 0; i < 4; ++i) {
            #pragma unroll
            for (int rr = 0; rr < 4; ++rr) {
                const int rl = wr * 64 + i * 16 + g4 * 4 + rr;
                const size_t r = (size_t)(row0 + rl);
                const float rn = stats[rl];
                #pragma unroll
                for (int j = 0; j < 4; ++j) {
                    const int c = wc * 64 + j * 16 + fr;
                    Yb[r * 256 + c] = f2bf(acc[i][j][rr] * rn);
                }
            }
        }
    }
}

// ---------------------------------------------------------------- width-1024 LN (+GELU), bf16 in/out
__global__ __launch_bounds__(256)
void ln1024_kernel(const bfu* __restrict__ X, const float* __restrict__ w,
                   const float* __restrict__ b, bfu* __restrict__ Y)
{
    __shared__ float sbuf[4];
    const int row = blockIdx.x;
    const bfu* xr = X + (size_t)row * 1024;

    ushort4 t4 = *(const ushort4*)(xr + threadIdx.x * 4);
    float v[4] = {bf2f(t4.x), bf2f(t4.y), bf2f(t4.z), bf2f(t4.w)};

    float s = v[0] + v[1] + v[2] + v[3];
    s = wave_sum(s);
    const int lane = threadIdx.x & 63, wid = threadIdx.x >> 6;
    if (lane == 0) sbuf[wid] = s;
    __syncthreads();
    const float mean = (sbuf[0] + sbuf[1] + sbuf[2] + sbuf[3]) * (1.f / 1024.f);

    float q = 0.f;
    #pragma unroll
    for (int j = 0; j < 4; ++j) { float d = v[j] - mean; q += d * d; }
    q = wave_sum(q);
    __syncthreads();
    if (lane == 0) sbuf[wid] = q;
    __syncthreads();
    const float var  = (sbuf[0] + sbuf[1] + sbuf[2] + sbuf[3]) * (1.f / 1024.f);
    const float rstd = rsqrtf(var + 1e-6f);

    ushort4 o;
    #pragma unroll
    for (int j = 0; j < 4; ++j) {
        const int c = threadIdx.x * 4 + j;
        float y = gelu_exact((v[j] - mean) * rstd * w[c] + b[c]);
        ((bfu*)&o)[j] = f2bf(y);
    }
    *(ushort4*)(Y + (size_t)row * 1024 + threadIdx.x * 4) = o;
}

// ---------------------------------------------------------------- causal attention, T=20, hd=64
// one wave per (batch, head). Vectorized ushort4 staging (16 lanes/row).
__global__ __launch_bounds__(64)
void attn_kernel(const bfu* __restrict__ qkv, bfu* __restrict__ out,
                 int B, int T, int H)
{
    __shared__ float qs[20][65];
    __shared__ float ks[20][65];
    __shared__ float vs[20][65];
    __shared__ float probs[64];

    const int blk = blockIdx.x;
    const int b = blk / H;
    const int h = blk % H;
    const int tid = threadIdx.x;

    const bfu* base0 = qkv + (size_t)(b * T) * 768 + h * 64;
    #pragma unroll
    for (int m = 0; m < 3; ++m) {
        const bfu* src = base0 + m * 256;
        float (*dst)[65] = (m == 0) ? qs : (m == 1) ? ks : vs;
        #pragma unroll
        for (int i = 0; i < 5; ++i) {
            const int idx = i * 64 + tid;       // 0..319 = 20 rows x 16 segs
            const int t = idx >> 4, s = (idx & 15) * 4;
            ushort4 u = *(const ushort4*)(src + (size_t)t * 768 + s);
            dst[t][s+0] = bf2f(u.x); dst[t][s+1] = bf2f(u.y);
            dst[t][s+2] = bf2f(u.z); dst[t][s+3] = bf2f(u.w);
        }
    }
    __syncthreads();

    for (int t = 0; t < T; ++t) {
        float sc = -INFINITY;
        if (tid <= t) {
            float s = 0.f;
            #pragma unroll
            for (int d = 0; d < 64; ++d) s = fmaf(qs[t][d], ks[tid][d], s);
            sc = s * 0.125f;
        }
        float m = sc;
        #pragma unroll
        for (int off = 32; off; off >>= 1) m = fmaxf(m, __shfl_xor(m, off, 64));
        float p = (tid <= t) ? expf(sc - m) : 0.f;
        float sum = p;
        #pragma unroll
        for (int off = 32; off; off >>= 1) sum += __shfl_xor(sum, off, 64);
        p /= sum;
        probs[tid] = p;
        __syncthreads();

        float o = 0.f;
        for (int s = 0; s <= t; ++s) o = fmaf(probs[s], vs[s][tid], o);
        out[(size_t)(b * T + t) * 256 + h * 64 + tid] = f2bf(o);
        __syncthreads();
    }
}

// ---------------------------------------------------------------- row L2 normalize, wave-per-row -> bf16
__global__ __launch_bounds__(256)
void l2norm_kernel(const float* __restrict__ X, bfu* __restrict__ Y)
{
    const int row  = blockIdx.x * 4 + (threadIdx.x >> 6);
    const int lane = threadIdx.x & 63;
    float4 v = *(const float4*)(X + (size_t)row * 256 + lane * 4);
    float n = sqrtf(wave_sum(v.x*v.x + v.y*v.y + v.z*v.z + v.w*v.w));
    n = 1.f / fmaxf(n, 1e-12f);
    ushort4 o = {f2bf(v.x*n), f2bf(v.y*n), f2bf(v.z*n), f2bf(v.w*n)};
    *(ushort4*)(Y + (size_t)row * 256 + lane * 4) = o;
}

// ---------------------------------------------------------------- driver
extern "C" void kernel_launch(void* const* d_in, const int* in_sizes, int n_in,
                              void* d_out, int out_size, void* d_ws, size_t ws_size,
                              hipStream_t stream)
{
    const float* x         = (const float*)d_in[0];
    const float* p1_w      = (const float*)d_in[1];
    const float* p1_b      = (const float*)d_in[2];
    const float* pln1_w    = (const float*)d_in[3];
    const float* pln1_b    = (const float*)d_in[4];
    const float* p2_w      = (const float*)d_in[5];
    const float* pln2_w    = (const float*)d_in[6];
    const float* pln2_b    = (const float*)d_in[7];
    const float* in_proj_w = (const float*)d_in[8];
    const float* in_proj_b = (const float*)d_in[9];
    const float* out_proj_w= (const float*)d_in[10];
    const float* out_proj_b= (const float*)d_in[11];
    const float* ln1_w     = (const float*)d_in[12];
    const float* ln1_b     = (const float*)d_in[13];
    const float* lin1_w    = (const float*)d_in[14];
    const float* lin1_b    = (const float*)d_in[15];
    const float* lin2_w    = (const float*)d_in[16];
    const float* lin2_b    = (const float*)d_in[17];
    const float* ln2_w     = (const float*)d_in[18];
    const float* ln2_b     = (const float*)d_in[19];
    const float* head_w    = (const float*)d_in[20];

    const int B = 2048, T = 20, E = 256, HID = 1024, CLS = 1000, L = 2, H = 4;
    const int M = B * T;   // 40960
    const int D = 2048;

    // ---- workspace carve-up ----
    char* p = (char*)d_ws;
    bfu*   xb     = (bfu*)p;    p += (size_t)M * D * 2;        // bf16 copy of x (dead after proj1)
    bfu*   h1b    = (bfu*)p;    p += (size_t)M * HID * 2;      // proj hidden / FF hidden bf16
    bfu*   wblk   = (bfu*)p;    p += (size_t)3932160 * 2;      // 6 bf16 weight buffers, contiguous
    bfu*   wnb    = (bfu*)p;    p += (size_t)1024 * E * 2;     // normalized head_w, padded rows
    float* pe     = (float*)p;  p += (size_t)T * 256 * 4;      // sincos PE table

    char* q = (char*)xb;       // aliases xb (used only after proj1 completes)
    float* h      = (float*)q;  q += (size_t)M * E * 4;        // fp32 residual state
    bfu*   hb     = (bfu*)q;    q += (size_t)M * E * 2;        // bf16 copy of h
    bfu*   abf    = (bfu*)q;    q += (size_t)M * E * 2;        // attention out bf16

    bfu* p1wb  = wblk;
    bfu* p2wb  = p1wb  + (size_t)HID * D;
    bfu* qkvwb = p2wb  + (size_t)E * HID;
    bfu* outwb = qkvwb + (size_t)L * 3 * E * E;
    bfu* l1wb  = outwb + (size_t)L * E * E;
    bfu* l2wb  = l1wb  + (size_t)L * 4 * E * E;

    float* out   = (float*)d_out;
    bfu*   qkvb  = (bfu*)d_out;        // [M,768] bf16 scratch inside d_out (dead before head GEMM)

    // ---- convert inputs/weights to bf16; build PE table ----
    cvt_kernel<<<2048, 256, 0, stream>>>(x, xb, M * D / 4);
    cvt6_kernel<<<2048, 256, 0, stream>>>(p1_w, p2_w, in_proj_w, out_proj_w, lin1_w, lin2_w, wblk);
    pe_kernel<<<T, 256, 0, stream>>>(pe);

    // ---- projector ----
    mfma_gemm256<false, true><<<dim3((M/256) * (HID/256)), 512, 0, stream>>>(
        xb, p1wb, p1_b, h1b, M, HID, D, 1.f, HID/256);
    ln1024_kernel<<<M, 256, 0, stream>>>(h1b, pln1_w, pln1_b, h1b);
    // proj2 + pln2 + PE fused -> h, hb
    mfma_gemm_ln<false, true, false><<<dim3(M/128), 512, 0, stream>>>(
        h1b, p2wb, nullptr, nullptr, pln2_w, pln2_b, pe, h, hb, M, HID, T);

    // ---- transformer layers (post-norm) ----
    for (int l = 0; l < L; ++l) {
        mfma_gemm256<false, true><<<dim3(3 * (M/256)), 512, 0, stream>>>(
            hb, qkvwb + (size_t)l * 3*E*E, in_proj_b + (size_t)l * 3*E, qkvb, M, 3*E, E, 1.f, 3);
        attn_kernel<<<B * H, 64, 0, stream>>>(qkvb, abf, B, T, H);
        // out_proj + bias + residual + ln1 fused -> h, hb
        mfma_gemm_ln<true, false, false><<<dim3(M/128), 512, 0, stream>>>(
            abf, outwb + (size_t)l * E*E, out_proj_b + (size_t)l * E, h,
            ln1_w + (size_t)l * E, ln1_b + (size_t)l * E, nullptr, h, hb, M, E, T);
        mfma_gemm256<true, true><<<dim3(4 * (M/256)), 512, 0, stream>>>(
            hb, l1wb + (size_t)l * 4*E*E, lin1_b + (size_t)l * 4*E, h1b, M, HID, E, 1.f, 4);
        if (l < L - 1) {
            // ff2 + bias + residual + ln2 fused -> h, hb
            mfma_gemm_ln<true, false, false><<<dim3(M/128), 512, 0, stream>>>(
                h1b, l2wb + (size_t)l * E*4*E, lin2_b + (size_t)l * E, h,
                ln2_w + (size_t)l * E, ln2_b + (size_t)l * E, nullptr, h, hb, M, HID, T);
        } else {
            // last layer: ff2 + ln2 + row-l2norm fused, bf16-only output
            mfma_gemm_ln<true, false, true><<<dim3(M/128), 512, 0, stream>>>(
                h1b, l2wb + (size_t)l * E*4*E, lin2_b + (size_t)l * E, h,
                ln2_w + (size_t)l * E, ln2_b + (size_t)l * E, nullptr, nullptr, hb, M, HID, T);
        }
    }

    // ---- head ----
    l2norm_kernel<<<CLS/4, 256, 0, stream>>>(head_w, wnb);   // wn = bf16(normalize(head_w)); pad rows junk (safe)
    mfma_gemm256<false, false><<<dim3(4 * (M/256)), 512, 0, stream>>>(
        hb, wnb, nullptr, out, M, CLS, E, 10.f, 4);
}

// Round 9
// 1173.942 us; speedup vs baseline: 1.0718x; 1.0718x over previous
//
#include <hip/hip_runtime.h>
#include <math.h>

#define CDIV(a,b) (((a)+(b)-1)/(b))

typedef unsigned short bfu;                                   // bf16 bits
typedef short   s16x8 __attribute__((ext_vector_type(8)));    // MFMA A/B frag (8 bf16)
typedef float   f32x4 __attribute__((ext_vector_type(4)));    // MFMA C/D frag

// async global->LDS, 16B per lane. LDS dst must be wave-uniform; HW writes base+lane*16.
#define GLOAD16(gp, lp) __builtin_amdgcn_global_load_lds( \
    (const __attribute__((address_space(1))) void*)(gp),  \
    (__attribute__((address_space(3))) void*)(lp), 16, 0, 0)

// ---------------------------------------------------------------- helpers
static __device__ __forceinline__ float gelu_exact(float x) {
    return 0.5f * x * (1.0f + erff(x * 0.7071067811865475f));
}
static __device__ __forceinline__ bfu f2bf(float x) {         // RNE f32->bf16
    unsigned int u = __float_as_uint(x);
    unsigned int r = u + 0x7fffu + ((u >> 16) & 1u);
    return (bfu)(r >> 16);
}
static __device__ __forceinline__ float bf2f(bfu b) {
    return __uint_as_float(((unsigned int)b) << 16);
}
static __device__ __forceinline__ float wave_sum(float v) {
    #pragma unroll
    for (int off = 32; off; off >>= 1) v += __shfl_xor(v, off, 64);
    return v;
}

// ---------------------------------------------------------------- fp32 -> bf16 convert (grid-stride)
__global__ __launch_bounds__(256)
void cvt_kernel(const float* __restrict__ in, bfu* __restrict__ out, int n4)
{
    int i = blockIdx.x * 256 + threadIdx.x;
    const int stride = gridDim.x * 256;
    for (; i < n4; i += stride) {
        float4 f = ((const float4*)in)[i];
        ushort4 o;
        o.x = f2bf(f.x); o.y = f2bf(f.y); o.z = f2bf(f.z); o.w = f2bf(f.w);
        ((ushort4*)out)[i] = o;
    }
}

// ---------------------------------------------------------------- fused weight convert (6 regions)
__global__ __launch_bounds__(256)
void cvt6_kernel(const float* __restrict__ s0, const float* __restrict__ s1,
                 const float* __restrict__ s2, const float* __restrict__ s3,
                 const float* __restrict__ s4, const float* __restrict__ s5,
                 bfu* __restrict__ dst)
{
    const int c0 = 524288;           // p1_w  1024*2048/4
    const int c1 = c0 + 65536;       // p2_w  256*1024/4
    const int c2 = c1 + 98304;       // in_proj 2*768*256/4
    const int c3 = c2 + 32768;       // out_proj 2*256*256/4
    const int c4 = c3 + 131072;      // lin1 2*1024*256/4
    const int c5 = c4 + 131072;      // lin2 2*256*1024/4
    int i = blockIdx.x * 256 + threadIdx.x;
    const int stride = gridDim.x * 256;
    for (; i < c5; i += stride) {
        const float* s; int base;
        if      (i < c0) { s = s0; base = 0;  }
        else if (i < c1) { s = s1; base = c0; }
        else if (i < c2) { s = s2; base = c1; }
        else if (i < c3) { s = s3; base = c2; }
        else if (i < c4) { s = s4; base = c3; }
        else             { s = s5; base = c4; }
        float4 f = ((const float4*)s)[i - base];
        ushort4 o;
        o.x = f2bf(f.x); o.y = f2bf(f.y); o.z = f2bf(f.z); o.w = f2bf(f.w);
        ((ushort4*)dst)[i] = o;
    }
}

// ---------------------------------------------------------------- sincos PE table [T,256]
__global__ __launch_bounds__(256)
void pe_kernel(float* __restrict__ pe)
{
    const int t = blockIdx.x;
    const int c = threadIdx.x;
    const float div = expf((float)(c & ~1) * (-9.210340371976184f / 256.0f));
    const float ang = (float)t * div;
    pe[t * 256 + c] = (c & 1) ? cosf(ang) : sinf(ang);
}

// ---------------------------------------------------------------- MFMA GEMM 128x256 deep pipeline
// C[M,N] = scale * epi(A[M,K] @ W[N,K]^T + bias). 128x256 tile, BK=32,
// 512 thr (8 waves 2Mx4N, each 64x64, acc[4][4]=64 AGPR). 2-buf LDS (48KB),
// stage(t+2) after compute(t), counted vmcnt(3). 3-term granule XOR swizzle
// both-sides. __launch_bounds__(512,4) caps regs at 128 -> 2 blocks/CU,
// 16 waves/CU (R8 occupancy fix: R5-R7 256^2 kernel was 1 block/CU,
// latency-bound at 3538 cyc/block-iter vs ~800 theoretical).
// Requires M%128==0, K%32==0, K>=64, N-tile cols bounds-checked on store;
// W rows up to tile edge must be readable (pad rows junk-safe).
template<bool GELU_EP, bool OUT_BF16>
__global__ __launch_bounds__(512, 4)
void mfma_gemmA(const bfu* __restrict__ A, const bfu* __restrict__ W,
                const float* __restrict__ bias, void* __restrict__ Cv,
                int M, int N, int K, float scale, int ntx)
{
    __shared__ bfu ldsA[2][4096];     // [dbuf][128 rows x 32]
    __shared__ bfu ldsW[2][8192];     // [dbuf][256 rows x 32]

    const int tid  = threadIdx.x;
    const int lane = tid & 63;
    const int wv   = tid >> 6;
    const int nwg  = gridDim.x;
    const int lid  = (nwg & 7) ? (int)blockIdx.x
                               : ((int)blockIdx.x & 7) * (nwg >> 3) + ((int)blockIdx.x >> 3);
    const int row0 = (lid / ntx) * 128;
    const int col0 = (lid % ntx) * 256;

    const int srow = wv * 16 + (lane >> 2);
    const int sk   = ((lane & 3) ^ ((lane >> 2) & 3) ^ (lane >> 4)) * 8;
    const bfu* aS  = A + (size_t)(row0 + srow) * K + sk;
    const bfu* wS0 = W + (size_t)(col0 + srow)        * K + sk;
    const bfu* wS1 = W + (size_t)(col0 + srow + 128)  * K + sk;
    const int dOff = wv * 512;

    const int wr = wv >> 2, wc = wv & 3;       // 2M x 4N, each wave 64x64
    const int fr = lane & 15;
    const int g4 = lane >> 4;
    const int slot = ((g4 ^ (fr & 3) ^ ((fr >> 2) & 3))) * 8;

    f32x4 acc[4][4];
    #pragma unroll
    for (int i = 0; i < 4; ++i)
        #pragma unroll
        for (int j = 0; j < 4; ++j) acc[i][j] = (f32x4)0.f;

    const int nt = K >> 5;

#define STAGEA_(b_, t_) do { \
    const size_t ko_ = (size_t)(t_) * 32; \
    GLOAD16(aS  + ko_, &ldsA[b_][dOff]); \
    GLOAD16(wS0 + ko_, &ldsW[b_][dOff]); \
    GLOAD16(wS1 + ko_, &ldsW[b_][4096 + dOff]); \
} while (0)

    STAGEA_(0, 0);
    STAGEA_(1, 1);

    int cur = 0;
    for (int t = 0; t < nt; ++t) {
        if (t + 1 < nt) asm volatile("s_waitcnt vmcnt(3)" ::: "memory");
        else            asm volatile("s_waitcnt vmcnt(0)" ::: "memory");
        asm volatile("s_barrier" ::: "memory");

        const bfu* Ab = ldsA[cur];
        const bfu* Wb = ldsW[cur];

        s16x8 bfr[4], afr[4];
        #pragma unroll
        for (int j = 0; j < 4; ++j)
            bfr[j] = *(const s16x8*)&Wb[(wc * 64 + j * 16 + fr) * 32 + slot];
        #pragma unroll
        for (int i = 0; i < 4; ++i)
            afr[i] = *(const s16x8*)&Ab[(wr * 64 + i * 16 + fr) * 32 + slot];

        __builtin_amdgcn_s_setprio(1);
        #pragma unroll
        for (int i = 0; i < 4; ++i)
            #pragma unroll
            for (int j = 0; j < 4; ++j)
                acc[i][j] = __builtin_amdgcn_mfma_f32_16x16x32_bf16(afr[i], bfr[j], acc[i][j], 0, 0, 0);
        __builtin_amdgcn_s_setprio(0);

        asm volatile("s_barrier" ::: "memory");
        if (t + 2 < nt) STAGEA_(cur, t + 2);
        cur ^= 1;
    }
#undef STAGEA_

    #pragma unroll
    for (int i = 0; i < 4; ++i) {
        const int r = row0 + wr * 64 + 16 * i + g4 * 4;
        #pragma unroll
        for (int j = 0; j < 4; ++j) {
            const int c = col0 + wc * 64 + 16 * j + fr;
            if (c < N) {
                const float bsum = bias ? bias[c] : 0.f;
                #pragma unroll
                for (int rr = 0; rr < 4; ++rr) {
                    float v = acc[i][j][rr] + bsum;
                    if (GELU_EP) v = gelu_exact(v);
                    v *= scale;
                    if (OUT_BF16) ((bfu*)Cv)[(size_t)(r + rr) * N + c] = f2bf(v);
                    else          ((float*)Cv)[(size_t)(r + rr) * N + c] = v;
                }
            }
        }
    }
}

// ---------------------------------------------------------------- MFMA GEMM 128x256 + fused LayerNorm
// Y = LN( A[M,K] @ W[256,K]^T + bias (+R) ) [*lnw+lnb] (+PE)  -> Yf fp32, Yb bf16
// L2N: additionally row-l2-normalize the LN output and write ONLY Yb.
// Verified R6/R7. Kept at (512,2) — epilogue register pressure.
template<bool RES, bool ADD_PE, bool L2N>
__global__ __launch_bounds__(512, 2)
void mfma_gemm_ln(const bfu* __restrict__ A, const bfu* __restrict__ W,
                  const float* __restrict__ bias, const float* __restrict__ R,
                  const float* __restrict__ lnw, const float* __restrict__ lnb,
                  const float* __restrict__ pe, float* __restrict__ Yf,
                  bfu* __restrict__ Yb, int M, int K, int T)
{
    __shared__ bfu ldsA[2][4096];     // [dbuf][128 rows x 32]
    __shared__ bfu ldsW[2][8192];     // [dbuf][256 rows x 32]

    const int tid  = threadIdx.x;
    const int lane = tid & 63;
    const int wv   = tid >> 6;
    const int nwg  = gridDim.x;
    const int lid  = (nwg & 7) ? (int)blockIdx.x
                               : ((int)blockIdx.x & 7) * (nwg >> 3) + ((int)blockIdx.x >> 3);
    const int row0 = lid * 128;

    const int srow = wv * 16 + (lane >> 2);
    const int sk   = ((lane & 3) ^ ((lane >> 2) & 3) ^ (lane >> 4)) * 8;
    const bfu* aS  = A + (size_t)(row0 + srow) * K + sk;
    const bfu* wS0 = W + (size_t)(srow)        * K + sk;
    const bfu* wS1 = W + (size_t)(srow + 128)  * K + sk;
    const int dOff = wv * 512;

    const int wr = wv >> 2, wc = wv & 3;       // 2M x 4N, each wave 64x64
    const int fr = lane & 15;
    const int g4 = lane >> 4;
    const int slot = ((g4 ^ (fr & 3) ^ ((fr >> 2) & 3))) * 8;

    f32x4 acc[4][4];
    #pragma unroll
    for (int i = 0; i < 4; ++i)
        #pragma unroll
        for (int j = 0; j < 4; ++j) acc[i][j] = (f32x4)0.f;

    const int nt = K >> 5;

#define STAGELN(b_, t_) do { \
    const size_t ko_ = (size_t)(t_) * 32; \
    GLOAD16(aS  + ko_, &ldsA[b_][dOff]); \
    GLOAD16(wS0 + ko_, &ldsW[b_][dOff]); \
    GLOAD16(wS1 + ko_, &ldsW[b_][4096 + dOff]); \
} while (0)

    STAGELN(0, 0);
    STAGELN(1, 1);

    int cur = 0;
    for (int t = 0; t < nt; ++t) {
        if (t + 1 < nt) asm volatile("s_waitcnt vmcnt(3)" ::: "memory");
        else            asm volatile("s_waitcnt vmcnt(0)" ::: "memory");
        asm volatile("s_barrier" ::: "memory");

        const bfu* Ab = ldsA[cur];
        const bfu* Wb = ldsW[cur];

        s16x8 bfr[4], afr[4];
        #pragma unroll
        for (int j = 0; j < 4; ++j)
            bfr[j] = *(const s16x8*)&Wb[(wc * 64 + j * 16 + fr) * 32 + slot];
        #pragma unroll
        for (int i = 0; i < 4; ++i)
            afr[i] = *(const s16x8*)&Ab[(wr * 64 + i * 16 + fr) * 32 + slot];

        __builtin_amdgcn_s_setprio(1);
        #pragma unroll
        for (int i = 0; i < 4; ++i)
            #pragma unroll
            for (int j = 0; j < 4; ++j)
                acc[i][j] = __builtin_amdgcn_mfma_f32_16x16x32_bf16(afr[i], bfr[j], acc[i][j], 0, 0, 0);
        __builtin_amdgcn_s_setprio(0);

        asm volatile("s_barrier" ::: "memory");
        if (t + 2 < nt) STAGELN(cur, t + 2);
        cur ^= 1;
    }
#undef STAGELN

    // ---- fused LN epilogue (rows complete: 256 cols in-block) ----
    float* red   = (float*)ldsA;       // sum[128][4] @0, sq[128][4] @512
    float* stats = red + 1024;         // mean[128] @0, rstd[128] @128

    float bj[4];
    #pragma unroll
    for (int j = 0; j < 4; ++j)
        bj[j] = bias ? bias[wc * 64 + j * 16 + fr] : 0.f;

    #pragma unroll
    for (int i = 0; i < 4; ++i) {
        #pragma unroll
        for (int rr = 0; rr < 4; ++rr) {
            const int rl = wr * 64 + i * 16 + g4 * 4 + rr;
            const size_t r = (size_t)(row0 + rl);
            float s = 0.f, q = 0.f;
            #pragma unroll
            for (int j = 0; j < 4; ++j) {
                float v = acc[i][j][rr] + bj[j];
                if (RES) v += R[r * 256 + (wc * 64 + j * 16 + fr)];
                acc[i][j][rr] = v;
                s += v; q += v * v;
            }
            #pragma unroll
            for (int off = 1; off < 16; off <<= 1) {
                s += __shfl_xor(s, off, 64);
                q += __shfl_xor(q, off, 64);
            }
            if (fr == 0) { red[rl * 4 + wc] = s; red[512 + rl * 4 + wc] = q; }
        }
    }
    __syncthreads();
    if (tid < 128) {
        const float s = red[tid*4+0] + red[tid*4+1] + red[tid*4+2] + red[tid*4+3];
        const float q = red[512+tid*4+0] + red[512+tid*4+1] + red[512+tid*4+2] + red[512+tid*4+3];
        const float mean = s * (1.f / 256.f);
        const float var  = q * (1.f / 256.f) - mean * mean;
        stats[tid]       = mean;
        stats[128 + tid] = rsqrtf(var + 1e-6f);
    }
    __syncthreads();

    float lw[4], lb[4];
    #pragma unroll
    for (int j = 0; j < 4; ++j) {
        const int c = wc * 64 + j * 16 + fr;
        lw[j] = lnw[c]; lb[j] = lnb[c];
    }
    #pragma unroll
    for (int i = 0; i < 4; ++i) {
        #pragma unroll
        for (int rr = 0; rr < 4; ++rr) {
            const int rl = wr * 64 + i * 16 + g4 * 4 + rr;
            const size_t r = (size_t)(row0 + rl);
            const float mean = stats[rl], rstd = stats[128 + rl];
            const int tmod = (int)(r % (size_t)T);
            float ysq = 0.f;
            #pragma unroll
            for (int j = 0; j < 4; ++j) {
                const int c = wc * 64 + j * 16 + fr;
                float y = (acc[i][j][rr] - mean) * rstd * lw[j] + lb[j];
                if (ADD_PE) y += pe[tmod * 256 + c];
                if (!L2N) {
                    Yf[r * 256 + c] = y;
                    Yb[r * 256 + c] = f2bf(y);
                } else {
                    acc[i][j][rr] = y;
                    ysq += y * y;
                }
            }
            if (L2N) {
                #pragma unroll
                for (int off = 1; off < 16; off <<= 1) ysq += __shfl_xor(ysq, off, 64);
                if (fr == 0) red[rl * 4 + wc] = ysq;
            }
        }
    }
    if (L2N) {
        __syncthreads();
        if (tid < 128) {
            const float n = sqrtf(red[tid*4+0] + red[tid*4+1] + red[tid*4+2] + red[tid*4+3]);
            stats[tid] = 1.f / fmaxf(n, 1e-12f);
        }
        __syncthreads();
        #pragma unroll
        for (int i = 0; i < 4; ++i) {
            #pragma unroll
            for (int rr = 0; rr < 4; ++rr) {
                const int rl = wr * 64 + i * 16 + g4 * 4 + rr;
                const size_t r = (size_t)(row0 + rl);
                const float rn = stats[rl];
                #pragma unroll
                for (int j = 0; j < 4; ++j) {
                    const int c = wc * 64 + j * 16 + fr;
                    Yb[r * 256 + c] = f2bf(acc[i][j][rr] * rn);
                }
            }
        }
    }
}

// ---------------------------------------------------------------- width-1024 LN (+GELU), bf16 in/out
__global__ __launch_bounds__(256)
void ln1024_kernel(const bfu* __restrict__ X, const float* __restrict__ w,
                   const float* __restrict__ b, bfu* __restrict__ Y)
{
    __shared__ float sbuf[4];
    const int row = blockIdx.x;
    const bfu* xr = X + (size_t)row * 1024;

    ushort4 t4 = *(const ushort4*)(xr + threadIdx.x * 4);
    float v[4] = {bf2f(t4.x), bf2f(t4.y), bf2f(t4.z), bf2f(t4.w)};

    float s = v[0] + v[1] + v[2] + v[3];
    s = wave_sum(s);
    const int lane = threadIdx.x & 63, wid = threadIdx.x >> 6;
    if (lane == 0) sbuf[wid] = s;
    __syncthreads();
    const float mean = (sbuf[0] + sbuf[1] + sbuf[2] + sbuf[3]) * (1.f / 1024.f);

    float q = 0.f;
    #pragma unroll
    for (int j = 0; j < 4; ++j) { float d = v[j] - mean; q += d * d; }
    q = wave_sum(q);
    __syncthreads();
    if (lane == 0) sbuf[wid] = q;
    __syncthreads();
    const float var  = (sbuf[0] + sbuf[1] + sbuf[2] + sbuf[3]) * (1.f / 1024.f);
    const float rstd = rsqrtf(var + 1e-6f);

    ushort4 o;
    #pragma unroll
    for (int j = 0; j < 4; ++j) {
        const int c = threadIdx.x * 4 + j;
        float y = gelu_exact((v[j] - mean) * rstd * w[c] + b[c]);
        ((bfu*)&o)[j] = f2bf(y);
    }
    *(ushort4*)(Y + (size_t)row * 1024 + threadIdx.x * 4) = o;
}

// ---------------------------------------------------------------- causal attention, T=20, hd=64
__global__ __launch_bounds__(64)
void attn_kernel(const bfu* __restrict__ qkv, bfu* __restrict__ out,
                 int B, int T, int H)
{
    __shared__ float qs[20][65];
    __shared__ float ks[20][65];
    __shared__ float vs[20][65];
    __shared__ float probs[64];

    const int blk = blockIdx.x;
    const int b = blk / H;
    const int h = blk % H;
    const int tid = threadIdx.x;

    const bfu* base0 = qkv + (size_t)(b * T) * 768 + h * 64;
    #pragma unroll
    for (int m = 0; m < 3; ++m) {
        const bfu* src = base0 + m * 256;
        float (*dst)[65] = (m == 0) ? qs : (m == 1) ? ks : vs;
        #pragma unroll
        for (int i = 0; i < 5; ++i) {
            const int idx = i * 64 + tid;       // 0..319 = 20 rows x 16 segs
            const int t = idx >> 4, s = (idx & 15) * 4;
            ushort4 u = *(const ushort4*)(src + (size_t)t * 768 + s);
            dst[t][s+0] = bf2f(u.x); dst[t][s+1] = bf2f(u.y);
            dst[t][s+2] = bf2f(u.z); dst[t][s+3] = bf2f(u.w);
        }
    }
    __syncthreads();

    for (int t = 0; t < T; ++t) {
        float sc = -INFINITY;
        if (tid <= t) {
            float s = 0.f;
            #pragma unroll
            for (int d = 0; d < 64; ++d) s = fmaf(qs[t][d], ks[tid][d], s);
            sc = s * 0.125f;
        }
        float m = sc;
        #pragma unroll
        for (int off = 32; off; off >>= 1) m = fmaxf(m, __shfl_xor(m, off, 64));
        float p = (tid <= t) ? expf(sc - m) : 0.f;
        float sum = p;
        #pragma unroll
        for (int off = 32; off; off >>= 1) sum += __shfl_xor(sum, off, 64);
        p /= sum;
        probs[tid] = p;
        __syncthreads();

        float o = 0.f;
        for (int s = 0; s <= t; ++s) o = fmaf(probs[s], vs[s][tid], o);
        out[(size_t)(b * T + t) * 256 + h * 64 + tid] = f2bf(o);
        __syncthreads();
    }
}

// ---------------------------------------------------------------- row L2 normalize, wave-per-row -> bf16
__global__ __launch_bounds__(256)
void l2norm_kernel(const float* __restrict__ X, bfu* __restrict__ Y)
{
    const int row  = blockIdx.x * 4 + (threadIdx.x >> 6);
    const int lane = threadIdx.x & 63;
    float4 v = *(const float4*)(X + (size_t)row * 256 + lane * 4);
    float n = sqrtf(wave_sum(v.x*v.x + v.y*v.y + v.z*v.z + v.w*v.w));
    n = 1.f / fmaxf(n, 1e-12f);
    ushort4 o = {f2bf(v.x*n), f2bf(v.y*n), f2bf(v.z*n), f2bf(v.w*n)};
    *(ushort4*)(Y + (size_t)row * 256 + lane * 4) = o;
}

// ---------------------------------------------------------------- driver
extern "C" void kernel_launch(void* const* d_in, const int* in_sizes, int n_in,
                              void* d_out, int out_size, void* d_ws, size_t ws_size,
                              hipStream_t stream)
{
    const float* x         = (const float*)d_in[0];
    const float* p1_w      = (const float*)d_in[1];
    const float* p1_b      = (const float*)d_in[2];
    const float* pln1_w    = (const float*)d_in[3];
    const float* pln1_b    = (const float*)d_in[4];
    const float* p2_w      = (const float*)d_in[5];
    const float* pln2_w    = (const float*)d_in[6];
    const float* pln2_b    = (const float*)d_in[7];
    const float* in_proj_w = (const float*)d_in[8];
    const float* in_proj_b = (const float*)d_in[9];
    const float* out_proj_w= (const float*)d_in[10];
    const float* out_proj_b= (const float*)d_in[11];
    const float* ln1_w     = (const float*)d_in[12];
    const float* ln1_b     = (const float*)d_in[13];
    const float* lin1_w    = (const float*)d_in[14];
    const float* lin1_b    = (const float*)d_in[15];
    const float* lin2_w    = (const float*)d_in[16];
    const float* lin2_b    = (const float*)d_in[17];
    const float* ln2_w     = (const float*)d_in[18];
    const float* ln2_b     = (const float*)d_in[19];
    const float* head_w    = (const float*)d_in[20];

    const int B = 2048, T = 20, E = 256, HID = 1024, CLS = 1000, L = 2, H = 4;
    const int M = B * T;   // 40960
    const int D = 2048;

    // ---- workspace carve-up ----
    char* p = (char*)d_ws;
    bfu*   xb     = (bfu*)p;    p += (size_t)M * D * 2;        // bf16 copy of x (dead after proj1)
    bfu*   h1b    = (bfu*)p;    p += (size_t)M * HID * 2;      // proj hidden / FF hidden bf16
    bfu*   wblk   = (bfu*)p;    p += (size_t)3932160 * 2;      // 6 bf16 weight buffers, contiguous
    bfu*   wnb    = (bfu*)p;    p += (size_t)1024 * E * 2;     // normalized head_w, padded rows
    float* pe     = (float*)p;  p += (size_t)T * 256 * 4;      // sincos PE table

    char* q = (char*)xb;       // aliases xb (used only after proj1 completes)
    float* h      = (float*)q;  q += (size_t)M * E * 4;        // fp32 residual state
    bfu*   hb     = (bfu*)q;    q += (size_t)M * E * 2;        // bf16 copy of h
    bfu*   abf    = (bfu*)q;    q += (size_t)M * E * 2;        // attention out bf16

    bfu* p1wb  = wblk;
    bfu* p2wb  = p1wb  + (size_t)HID * D;
    bfu* qkvwb = p2wb  + (size_t)E * HID;
    bfu* outwb = qkvwb + (size_t)L * 3 * E * E;
    bfu* l1wb  = outwb + (size_t)L * E * E;
    bfu* l2wb  = l1wb  + (size_t)L * 4 * E * E;

    float* out   = (float*)d_out;
    bfu*   qkvb  = (bfu*)d_out;        // [M,768] bf16 scratch inside d_out (dead before head GEMM)

    // ---- convert inputs/weights to bf16; build PE table ----
    cvt_kernel<<<2048, 256, 0, stream>>>(x, xb, M * D / 4);
    cvt6_kernel<<<2048, 256, 0, stream>>>(p1_w, p2_w, in_proj_w, out_proj_w, lin1_w, lin2_w, wblk);
    pe_kernel<<<T, 256, 0, stream>>>(pe);

    // ---- projector ----
    mfma_gemmA<false, true><<<dim3((M/128) * (HID/256)), 512, 0, stream>>>(
        xb, p1wb, p1_b, h1b, M, HID, D, 1.f, HID/256);
    ln1024_kernel<<<M, 256, 0, stream>>>(h1b, pln1_w, pln1_b, h1b);
    // proj2 + pln2 + PE fused -> h, hb
    mfma_gemm_ln<false, true, false><<<dim3(M/128), 512, 0, stream>>>(
        h1b, p2wb, nullptr, nullptr, pln2_w, pln2_b, pe, h, hb, M, HID, T);

    // ---- transformer layers (post-norm) ----
    for (int l = 0; l < L; ++l) {
        mfma_gemmA<false, true><<<dim3((M/128) * 3), 512, 0, stream>>>(
            hb, qkvwb + (size_t)l * 3*E*E, in_proj_b + (size_t)l * 3*E, qkvb, M, 3*E, E, 1.f, 3);
        attn_kernel<<<B * H, 64, 0, stream>>>(qkvb, abf, B, T, H);
        // out_proj + bias + residual + ln1 fused -> h, hb
        mfma_gemm_ln<true, false, false><<<dim3(M/128), 512, 0, stream>>>(
            abf, outwb + (size_t)l * E*E, out_proj_b + (size_t)l * E, h,
            ln1_w + (size_t)l * E, ln1_b + (size_t)l * E, nullptr, h, hb, M, E, T);
        mfma_gemmA<true, true><<<dim3((M/128) * 4), 512, 0, stream>>>(
            hb, l1wb + (size_t)l * 4*E*E, lin1_b + (size_t)l * 4*E, h1b, M, HID, E, 1.f, 4);
        if (l < L - 1) {
            // ff2 + bias + residual + ln2 fused -> h, hb
            mfma_gemm_ln<true, false, false><<<dim3(M/128), 512, 0, stream>>>(
                h1b, l2wb + (size_t)l * E*4*E, lin2_b + (size_t)l * E, h,
                ln2_w + (size_t)l * E, ln2_b + (size_t)l * E, nullptr, h, hb, M, HID, T);
        } else {
            // last layer: ff2 + ln2 + row-l2norm fused, bf16-only output
            mfma_gemm_ln<true, false, true><<<dim3(M/128), 512, 0, stream>>>(
                h1b, l2wb + (size_t)l * E*4*E, lin2_b + (size_t)l * E, h,
                ln2_w + (size_t)l * E, ln2_b + (size_t)l * E, nullptr, nullptr, hb, M, HID, T);
        }
    }

    // ---- head ----
    l2norm_kernel<<<CLS/4, 256, 0, stream>>>(head_w, wnb);   // wn = bf16(normalize(head_w)); pad rows junk (safe)
    mfma_gemmA<false, false><<<dim3((M/128) * 4), 512, 0, stream>>>(
        hb, wnb, nullptr, out, M, CLS, E, 10.f, 4);
}